// Round 12
// baseline (73.682 us; speedup 1.0000x reference)
//
#include <hip/hip_runtime.h>
#include <math.h>

// ContrastiveLoss: B=16384, D=64, fp32 in, scalar fp32 out.
// loss_i = logsumexp_j(sim[i,j]) - sim[i,i];  out = mean_i(loss_i)
// sim = normalize_rows(A) @ normalize_rows(B)^T / 0.07
//
// Round 12: R11's amortization (stage B chunk ONCE per block, then RBLOOP=4
// A row-blocks) with race-hardened sync. R11 tripped the determinism check
// (NaN on some launches): suspected staging race -- barrier placed right
// after global_load_lds issues without a guaranteed vmcnt drain, so waves
// could ds_read LDS before the DMA landed. Fix: restore R10's proven
// pre-barrier mix (staging, then A-frag loads, THEN barrier) and force the
// drain with an explicit s_waitcnt vmcnt(0) before __syncthreads.

#define NROWS 16384
#define DIM 64
#define INV_T 14.285714285714286f           // 1/0.07
#define LOG2E 1.44269504088896340736f
#define LN2   0.69314718055994530942f
#define SCALE (INV_T * LOG2E)               // fold 1/T and log2(e) into A

#define JC     64                           // j-chunks; == wavefront size
#define JPC    (NROWS / JC)                 // 256 j per chunk
#define NTILES (JPC / 16)                   // 16 B-tiles per chunk
#define TT     2                            // A row-tiles per wave (32 rows)
#define WR     (TT * 16)                    // 32 rows per wave
#define NWAVE  8                            // waves per block
#define BROWS  (NWAVE * WR)                 // 256 rows per block-iteration
#define RBLOOP 4                            // row-blocks per block (amortize)
#define ROWB   (DIM * 2)                    // 128 bytes per bf16 row
#define LDSB   (JPC * ROWB)                 // 32 KiB
#define TILB   (16 * ROWB)                  // 2048 B per 16-row tile

typedef __attribute__((ext_vector_type(8))) short bf16x8;  // 8 bf16 = 4 VGPRs
typedef __attribute__((ext_vector_type(4))) float f32x4;

static __device__ __forceinline__ unsigned short f2bf(float f) {
    unsigned int u = __float_as_uint(f);
    unsigned int r = (u + 0x7fffu + ((u >> 16) & 1u)) >> 16;   // RNE
    return (unsigned short)r;
}

// ------- kernel 1: normalize rows of BOTH inputs -> bf16 (A pre-scaled) ----
__global__ __launch_bounds__(256) void nrm_bf16_kernel(
        const float* __restrict__ A, const float* __restrict__ B,
        unsigned short* __restrict__ Ab, unsigned short* __restrict__ Bb) {
    int wid  = (blockIdx.x * 256 + threadIdx.x) >> 6;   // 0..2*NROWS-1
    int lane = threadIdx.x & 63;
    const float* in;
    unsigned short* out;
    float scale;
    int row;
    if (wid < NROWS) { in = A; out = Ab; scale = SCALE; row = wid; }
    else             { in = B; out = Bb; scale = 1.0f;  row = wid - NROWS; }
    float x  = in[row * DIM + lane];
    float ss = x * x;
    #pragma unroll
    for (int m = 32; m >= 1; m >>= 1) ss += __shfl_xor(ss, m, 64);
    out[row * DIM + lane] = f2bf(x * rsqrtf(ss) * scale);
}

// -------- kernel 2: LDS-staged MFMA sim tiles + exp2 row-sum partials ------
// One block = one j-chunk staged once + RBLOOP row-blocks of A.
__global__ __launch_bounds__(NWAVE * 64) void simexp_kernel(
        const unsigned short* __restrict__ Ab,
        const unsigned short* __restrict__ Bb,
        float* __restrict__ partials) {
    __shared__ __align__(1024) unsigned char lds[LDSB];
    const int lane = threadIdx.x & 63;
    const int wid  = threadIdx.x >> 6;                  // wave in block
    const int jc   = blockIdx.x & (JC - 1);
    const int rbb  = blockIdx.x / JC;                   // 0..15
    const int lr   = lane & 15;                         // fragment row/col
    const int lk   = lane >> 4;                         // k-group (x8 bf16)

    // ---- stage B chunk ONCE: linear LDS dest, XOR-permuted global src ----
    // LDS(row, col16) holds global(row, col16 ^ (row&7)); each instr covers
    // 8 rows (1 KiB), so row&7 == lane>>3 inside the instr.  (validated r5)
    const unsigned char* gB = (const unsigned char*)Bb + (size_t)jc * JPC * ROWB;
    const int perm = ((lane >> 3) << 7) | ((((lane & 7) ^ (lane >> 3))) << 4);
    #pragma unroll
    for (int i = 0; i < LDSB / 1024 / NWAVE; ++i) {     // 4 slabs per wave
        const int off = (wid * (LDSB / 1024 / NWAVE) + i) * 1024;
        __builtin_amdgcn_global_load_lds(
            (const __attribute__((address_space(1))) void*)(gB + off + perm),
            (__attribute__((address_space(3))) void*)(&lds[off]),
            16, 0, 0);
    }

    // ---- A fragments for row-block 0 (overlap the staging latency) -------
    bf16x8 a[TT][2];
    {
        const int i00 = rbb * RBLOOP * BROWS + wid * WR;
        #pragma unroll
        for (int t = 0; t < TT; ++t) {
            const unsigned short* ap =
                Ab + (size_t)(i00 + t * 16 + lr) * DIM + lk * 8;
            a[t][0] = *(const bf16x8*)(ap);
            a[t][1] = *(const bf16x8*)(ap + 32);
        }
    }

    // ds_read bases: row lr, col16 = lk (frag0) / lk^4 (frag1), un-swizzled
    // via the same XOR; loop-invariant since row&7 == lr&7 for every tile.
    const unsigned char* lp0 = &lds[lr * ROWB + (((lk    ) ^ (lr & 7)) << 4)];
    const unsigned char* lp1 = &lds[lr * ROWB + (((lk ^ 4) ^ (lr & 7)) << 4)];
    const f32x4 zero = {0.f, 0.f, 0.f, 0.f};

    // Force the staging DMA (and A loads) to be complete before ANY wave
    // crosses the barrier -- do not rely on the compiler's barrier drain.
    asm volatile("s_waitcnt vmcnt(0)" ::: "memory");
    __syncthreads();

    for (int it = 0; it < RBLOOP; ++it) {
        const int i0 = (rbb * RBLOOP + it) * BROWS + wid * WR;

        float es[TT][4];
        #pragma unroll
        for (int t = 0; t < TT; ++t)
            #pragma unroll
            for (int r = 0; r < 4; ++r) es[t][r] = 0.0f;

        // ---- prologue: tile 0 -> accp ----
        bf16x8 c0 = *(const bf16x8*)(lp0);
        bf16x8 c1 = *(const bf16x8*)(lp1);
        f32x4 accp[TT];
        #pragma unroll
        for (int t = 0; t < TT; ++t) {
            accp[t] = __builtin_amdgcn_mfma_f32_16x16x32_bf16(a[t][0], c0, zero, 0, 0, 0);
            accp[t] = __builtin_amdgcn_mfma_f32_16x16x32_bf16(a[t][1], c1, accp[t], 0, 0, 0);
        }

        // ---- steady state: ds_read(jt) | exp(jt-1) | MFMA(jt) ----
        for (int jt = 1; jt < NTILES; ++jt) {
            bf16x8 n0 = *(const bf16x8*)(lp0 + jt * TILB);
            bf16x8 n1 = *(const bf16x8*)(lp1 + jt * TILB);
            #pragma unroll
            for (int t = 0; t < TT; ++t)
                #pragma unroll
                for (int r = 0; r < 4; ++r)
                    es[t][r] += __builtin_amdgcn_exp2f(accp[t][r]);
            #pragma unroll
            for (int t = 0; t < TT; ++t) {
                accp[t] = __builtin_amdgcn_mfma_f32_16x16x32_bf16(a[t][0], n0, zero, 0, 0, 0);
                accp[t] = __builtin_amdgcn_mfma_f32_16x16x32_bf16(a[t][1], n1, accp[t], 0, 0, 0);
            }
        }
        // ---- epilogue: exp of last tile ----
        #pragma unroll
        for (int t = 0; t < TT; ++t)
            #pragma unroll
            for (int r = 0; r < 4; ++r)
                es[t][r] += __builtin_amdgcn_exp2f(accp[t][r]);

        // ---- prefetch next row-block's A fragments (hide under reduce) ---
        if (it + 1 < RBLOOP) {
            const int i0n = (rbb * RBLOOP + it + 1) * BROWS + wid * WR;
            #pragma unroll
            for (int t = 0; t < TT; ++t) {
                const unsigned short* ap =
                    Ab + (size_t)(i0n + t * 16 + lr) * DIM + lk * 8;
                a[t][0] = *(const bf16x8*)(ap);
                a[t][1] = *(const bf16x8*)(ap + 32);
            }
        }

        // ---- reduce across the 16 lanes sharing lk; write partials ----
        #pragma unroll
        for (int t = 0; t < TT; ++t)
            #pragma unroll
            for (int r = 0; r < 4; ++r) {
                float v = es[t][r];
                v += __shfl_xor(v, 1, 64);
                v += __shfl_xor(v, 2, 64);
                v += __shfl_xor(v, 4, 64);
                v += __shfl_xor(v, 8, 64);
                es[t][r] = v;
            }
        if (lr == 0) {                                  // lanes 0,16,32,48
            float* pout = partials + (size_t)jc * NROWS + i0;
            #pragma unroll
            for (int t = 0; t < TT; ++t) {
                f32x4 v = {es[t][0], es[t][1], es[t][2], es[t][3]};
                *(f32x4*)(pout + t * 16 + lk * 4) = v;  // rows lk*4..lk*4+3
            }
        }
    }
}

// -------- kernel 3: per-row loss; lane-parallel partial sum (JC==64) -------
__global__ __launch_bounds__(256) void rowloss_kernel(
        const float* __restrict__ A, const float* __restrict__ B,
        const float* __restrict__ partials, float* __restrict__ rowloss) {
    int row  = (blockIdx.x * 256 + threadIdx.x) >> 6;
    int lane = threadIdx.x & 63;
    float a = A[row * DIM + lane];
    float b = B[row * DIM + lane];
    float saa = a * a, sbb = b * b, sab = a * b;
    float S   = partials[(size_t)lane * NROWS + row];   // one chunk per lane
    #pragma unroll
    for (int m = 32; m >= 1; m >>= 1) {
        saa += __shfl_xor(saa, m, 64);
        sbb += __shfl_xor(sbb, m, 64);
        sab += __shfl_xor(sab, m, 64);
        S   += __shfl_xor(S,   m, 64);
    }
    if (lane == 0) {
        float diag = sab * rsqrtf(saa * sbb);           // exact fp32 cos-sim
        rowloss[row] = LN2 * __builtin_amdgcn_logf(S) - diag * INV_T;
    }
}

// -------- kernel 4: deterministic mean over 16384 row losses ---------------
__global__ __launch_bounds__(1024) void mean_kernel(
        const float* __restrict__ rowloss, float* __restrict__ out) {
    float s = 0.f;
    for (int idx = threadIdx.x; idx < NROWS; idx += 1024) s += rowloss[idx];
    __shared__ float red[16];
    #pragma unroll
    for (int m = 32; m >= 1; m >>= 1) s += __shfl_xor(s, m, 64);
    if ((threadIdx.x & 63) == 0) red[threadIdx.x >> 6] = s;
    __syncthreads();
    if (threadIdx.x < 16) {
        float t = red[threadIdx.x];
        #pragma unroll
        for (int m = 8; m >= 1; m >>= 1) t += __shfl_xor(t, m, 16);
        if (threadIdx.x == 0) out[0] = t * (1.0f / NROWS);
    }
}

extern "C" void kernel_launch(void* const* d_in, const int* in_sizes, int n_in,
                              void* d_out, int out_size, void* d_ws, size_t ws_size,
                              hipStream_t stream) {
    const float* A  = (const float*)d_in[0];
    const float* Bm = (const float*)d_in[1];
    float* out = (float*)d_out;

    unsigned short* Ab = (unsigned short*)d_ws;                 // 2 MiB
    unsigned short* Bb = Ab + (size_t)NROWS * DIM;              // 2 MiB
    float* partials    = (float*)(Bb + (size_t)NROWS * DIM);    // 4 MiB
    float* rowloss     = partials + (size_t)JC * NROWS;         // 64 KiB

    nrm_bf16_kernel<<<2 * NROWS / 4, 256, 0, stream>>>(A, Bm, Ab, Bb);
    simexp_kernel<<<JC * (NROWS / (BROWS * RBLOOP)), NWAVE * 64, 0, stream>>>(
        Ab, Bb, partials);
    rowloss_kernel<<<NROWS / 4, 256, 0, stream>>>(A, Bm, partials, rowloss);
    mean_kernel<<<1, 1024, 0, stream>>>(rowloss, out);
}

// Round 13
// 64.270 us; speedup vs baseline: 1.1464x; 1.1464x over previous
//
#include <hip/hip_runtime.h>
#include <math.h>

// ContrastiveLoss: B=16384, D=64, fp32 in, scalar fp32 out.
// loss_i = logsumexp_j(sim[i,j]) - sim[i,i];  out = mean_i(loss_i)
// sim = normalize_rows(A) @ normalize_rows(B)^T / 0.07
//
// Round 13: R9 structure verbatim (best: 52us simexp, 56 VGPR, race-free),
// with the transcendental REMOVED via the Schraudolph float-reinterpret exp:
// R9/R10's exact 52.0us plateau across different schedules = issue-port wall
// (trans 4096x16 + VALU 59K = 124K ~= the full 125K cycle budget; VALUBusy's
// gfx94x formula doesn't count trans execution). Fix: pre-scale A by
// INV_T*LOG2E*2^23 so the MFMA accumulator IS 2^23*x; feed MFMA C the bias
// (127-sigma)*2^23; then es += as_float((int)acc) -- cvt+add (4cyc VALU)
// replaces exp+add (~18cyc). Max rel err +-3.0% -> |loss err| <= 0.03 << 0.225.

#define NROWS 16384
#define DIM 64
#define INV_T 14.285714285714286f           // 1/0.07
#define LOG2E 1.44269504088896340736f
#define LN2   0.69314718055994530942f
// A pre-scale: INV_T * LOG2E * 2^23  (MFMA acc = 2^23 * log2-logit)
#define SCALE (INV_T * LOG2E * 8388608.0f)
// Schraudolph bias: (127 - 0.0432) * 2^23, balanced max rel error +-3.0%
#define BIASF 1064990828.0f

#define JC     64                           // j-chunks; == wavefront size
#define JPC    (NROWS / JC)                 // 256 j per chunk
#define NTILES (JPC / 16)                   // 16 B-tiles per chunk
#define TT     2                            // A row-tiles per wave (32 rows)
#define WR     (TT * 16)                    // 32 rows per wave
#define NWAVE  8                            // waves per block
#define BROWS  (NWAVE * WR)                 // 256 rows per block
#define ROWB   (DIM * 2)                    // 128 bytes per bf16 row
#define LDSB   (JPC * ROWB)                 // 32 KiB
#define TILB   (16 * ROWB)                  // 2048 B per 16-row tile

typedef __attribute__((ext_vector_type(8))) short bf16x8;  // 8 bf16 = 4 VGPRs
typedef __attribute__((ext_vector_type(4))) float f32x4;

static __device__ __forceinline__ unsigned short f2bf(float f) {
    unsigned int u = __float_as_uint(f);
    unsigned int r = (u + 0x7fffu + ((u >> 16) & 1u)) >> 16;   // RNE
    return (unsigned short)r;
}

// ------- kernel 1: normalize rows of BOTH inputs -> bf16 (A pre-scaled) ----
__global__ __launch_bounds__(256) void nrm_bf16_kernel(
        const float* __restrict__ A, const float* __restrict__ B,
        unsigned short* __restrict__ Ab, unsigned short* __restrict__ Bb) {
    int wid  = (blockIdx.x * 256 + threadIdx.x) >> 6;   // 0..2*NROWS-1
    int lane = threadIdx.x & 63;
    const float* in;
    unsigned short* out;
    float scale;
    int row;
    if (wid < NROWS) { in = A; out = Ab; scale = SCALE; row = wid; }
    else             { in = B; out = Bb; scale = 1.0f;  row = wid - NROWS; }
    float x  = in[row * DIM + lane];
    float ss = x * x;
    #pragma unroll
    for (int m = 32; m >= 1; m >>= 1) ss += __shfl_xor(ss, m, 64);
    out[row * DIM + lane] = f2bf(x * rsqrtf(ss) * scale);
}

// -------- kernel 2: LDS-staged MFMA sim tiles + bit-exp row-sum partials ---
__global__ __launch_bounds__(NWAVE * 64) void simexp_kernel(
        const unsigned short* __restrict__ Ab,
        const unsigned short* __restrict__ Bb,
        float* __restrict__ partials) {
    __shared__ __align__(1024) unsigned char lds[LDSB];
    const int lane = threadIdx.x & 63;
    const int wid  = threadIdx.x >> 6;                  // wave in block
    const int jc   = blockIdx.x & (JC - 1);
    const int rb   = blockIdx.x / JC;
    const int i0   = rb * BROWS + wid * WR;             // wave's first A row
    const int lr   = lane & 15;                         // fragment row/col
    const int lk   = lane >> 4;                         // k-group (x8 bf16)

    // ---- stage B chunk: linear LDS dest, XOR-permuted global source ------
    // LDS(row, col16) holds global(row, col16 ^ (row&7)); each instr covers
    // 8 rows (1 KiB), so row&7 == lane>>3 inside the instr.  (validated r5)
    const unsigned char* gB = (const unsigned char*)Bb + (size_t)jc * JPC * ROWB;
    const int perm = ((lane >> 3) << 7) | ((((lane & 7) ^ (lane >> 3))) << 4);
    #pragma unroll
    for (int i = 0; i < LDSB / 1024 / NWAVE; ++i) {     // 4 slabs per wave
        const int off = (wid * (LDSB / 1024 / NWAVE) + i) * 1024;
        __builtin_amdgcn_global_load_lds(
            (const __attribute__((address_space(1))) void*)(gB + off + perm),
            (__attribute__((address_space(3))) void*)(&lds[off]),
            16, 0, 0);
    }

    // ---- A fragments (global/L2 loads overlap the staging latency) -------
    bf16x8 a[TT][2];
    #pragma unroll
    for (int t = 0; t < TT; ++t) {
        const unsigned short* ap = Ab + (size_t)(i0 + t * 16 + lr) * DIM + lk * 8;
        a[t][0] = *(const bf16x8*)(ap);
        a[t][1] = *(const bf16x8*)(ap + 32);
    }

    float es[TT][4];
    #pragma unroll
    for (int t = 0; t < TT; ++t)
        #pragma unroll
        for (int r = 0; r < 4; ++r) es[t][r] = 0.0f;

    __syncthreads();                                    // staging complete

    // ds_read bases: row lr, col16 = lk (frag0) / lk^4 (frag1), un-swizzled
    // via the same XOR; loop-invariant since row&7 == lr&7 for every tile.
    const unsigned char* lp0 = &lds[lr * ROWB + (((lk    ) ^ (lr & 7)) << 4)];
    const unsigned char* lp1 = &lds[lr * ROWB + (((lk ^ 4) ^ (lr & 7)) << 4)];

    // MFMA C input = Schraudolph bias: acc = 2^23*x + (127-sigma)*2^23.
    const f32x4 bias = {BIASF, BIASF, BIASF, BIASF};

    // ---- prologue: tile 0 -> accp ----
    bf16x8 c0 = *(const bf16x8*)(lp0);
    bf16x8 c1 = *(const bf16x8*)(lp1);
    f32x4 accp[TT];
    #pragma unroll
    for (int t = 0; t < TT; ++t) {
        accp[t] = __builtin_amdgcn_mfma_f32_16x16x32_bf16(a[t][0], c0, bias, 0, 0, 0);
        accp[t] = __builtin_amdgcn_mfma_f32_16x16x32_bf16(a[t][1], c1, accp[t], 0, 0, 0);
    }

    // ---- steady state: ds_read(jt) | bit-exp(jt-1) | MFMA(jt) ----
    for (int jt = 1; jt < NTILES; ++jt) {
        bf16x8 n0 = *(const bf16x8*)(lp0 + jt * TILB);
        bf16x8 n1 = *(const bf16x8*)(lp1 + jt * TILB);
        #pragma unroll
        for (int t = 0; t < TT; ++t)
            #pragma unroll
            for (int r = 0; r < 4; ++r)
                es[t][r] += __int_as_float((int)accp[t][r]);
        #pragma unroll
        for (int t = 0; t < TT; ++t) {
            accp[t] = __builtin_amdgcn_mfma_f32_16x16x32_bf16(a[t][0], n0, bias, 0, 0, 0);
            accp[t] = __builtin_amdgcn_mfma_f32_16x16x32_bf16(a[t][1], n1, accp[t], 0, 0, 0);
        }
    }
    // ---- epilogue: bit-exp of last tile ----
    #pragma unroll
    for (int t = 0; t < TT; ++t)
        #pragma unroll
        for (int r = 0; r < 4; ++r)
            es[t][r] += __int_as_float((int)accp[t][r]);

    // es[t][r]: partial over this lane's 16-col slice of row i0+t*16+lk*4+r.
    #pragma unroll
    for (int t = 0; t < TT; ++t)
        #pragma unroll
        for (int r = 0; r < 4; ++r) {
            float v = es[t][r];
            v += __shfl_xor(v, 1, 64);
            v += __shfl_xor(v, 2, 64);
            v += __shfl_xor(v, 4, 64);
            v += __shfl_xor(v, 8, 64);
            es[t][r] = v;
        }

    if (lr == 0) {                                      // lanes 0,16,32,48
        float* pout = partials + (size_t)jc * NROWS + i0;
        #pragma unroll
        for (int t = 0; t < TT; ++t) {
            f32x4 v = {es[t][0], es[t][1], es[t][2], es[t][3]};
            *(f32x4*)(pout + t * 16 + lk * 4) = v;      // rows lk*4..lk*4+3
        }
    }
}

// -------- kernel 3: per-row loss; lane-parallel partial sum (JC==64) -------
__global__ __launch_bounds__(256) void rowloss_kernel(
        const float* __restrict__ A, const float* __restrict__ B,
        const float* __restrict__ partials, float* __restrict__ rowloss) {
    int row  = (blockIdx.x * 256 + threadIdx.x) >> 6;
    int lane = threadIdx.x & 63;
    float a = A[row * DIM + lane];
    float b = B[row * DIM + lane];
    float saa = a * a, sbb = b * b, sab = a * b;
    float S   = partials[(size_t)lane * NROWS + row];   // one chunk per lane
    #pragma unroll
    for (int m = 32; m >= 1; m >>= 1) {
        saa += __shfl_xor(saa, m, 64);
        sbb += __shfl_xor(sbb, m, 64);
        sab += __shfl_xor(sab, m, 64);
        S   += __shfl_xor(S,   m, 64);
    }
    if (lane == 0) {
        float diag = sab * rsqrtf(saa * sbb);           // exact fp32 cos-sim
        rowloss[row] = LN2 * __builtin_amdgcn_logf(S) - diag * INV_T;
    }
}

// -------- kernel 4: deterministic mean over 16384 row losses ---------------
__global__ __launch_bounds__(1024) void mean_kernel(
        const float* __restrict__ rowloss, float* __restrict__ out) {
    float s = 0.f;
    for (int idx = threadIdx.x; idx < NROWS; idx += 1024) s += rowloss[idx];
    __shared__ float red[16];
    #pragma unroll
    for (int m = 32; m >= 1; m >>= 1) s += __shfl_xor(s, m, 64);
    if ((threadIdx.x & 63) == 0) red[threadIdx.x >> 6] = s;
    __syncthreads();
    if (threadIdx.x < 16) {
        float t = red[threadIdx.x];
        #pragma unroll
        for (int m = 8; m >= 1; m >>= 1) t += __shfl_xor(t, m, 16);
        if (threadIdx.x == 0) out[0] = t * (1.0f / NROWS);
    }
}

extern "C" void kernel_launch(void* const* d_in, const int* in_sizes, int n_in,
                              void* d_out, int out_size, void* d_ws, size_t ws_size,
                              hipStream_t stream) {
    const float* A  = (const float*)d_in[0];
    const float* Bm = (const float*)d_in[1];
    float* out = (float*)d_out;

    unsigned short* Ab = (unsigned short*)d_ws;                 // 2 MiB
    unsigned short* Bb = Ab + (size_t)NROWS * DIM;              // 2 MiB
    float* partials    = (float*)(Bb + (size_t)NROWS * DIM);    // 4 MiB
    float* rowloss     = partials + (size_t)JC * NROWS;         // 64 KiB

    nrm_bf16_kernel<<<2 * NROWS / 4, 256, 0, stream>>>(A, Bm, Ab, Bb);
    simexp_kernel<<<(NROWS / BROWS) * JC, NWAVE * 64, 0, stream>>>(Ab, Bb, partials);
    rowloss_kernel<<<NROWS / 4, 256, 0, stream>>>(A, Bm, partials, rowloss);
    mean_kernel<<<1, 1024, 0, stream>>>(rowloss, out);
}

// Round 14
// 57.256 us; speedup vs baseline: 1.2869x; 1.1225x over previous
//
#include <hip/hip_runtime.h>
#include <math.h>

// ContrastiveLoss: B=16384, D=64, fp32 in, scalar fp32 out.
// loss_i = logsumexp_j(sim[i,j]) - sim[i,i];  out = mean_i(loss_i)
// sim = normalize_rows(A) @ normalize_rows(B)^T / 0.07
//
// Round 14: amortize per-wave overhead. R13 fit: main-loop VALU is only ~16K
// cyc/SIMD of the 43K busy -- the rest is per-wave ramp (staging addr, A-frags,
// prologue, reduce, write) paid every 8K elements. Fix: JPC 256->512 (64KB LDS
// chunk, staged once) + RBLOOP=2 row-blocks per block -> 32K elements/wave,
// overhead ~50%->~20%. Grid 1024, LDS caps 2 blocks/CU = 16 waves/CU (above
// the measured 11-wave average). Sync = R12's proven order (stage, A-frags,
// drain, barrier) with __builtin_amdgcn_s_waitcnt(0x0f70) instead of the asm
// "memory" clobber that inflated R12 to 116 VGPR. Schraudolph bit-exp kept
// (R13, absmax 0.0625 vs 0.225 threshold).

#define NROWS 16384
#define DIM 64
#define INV_T 14.285714285714286f           // 1/0.07
#define LOG2E 1.44269504088896340736f
#define LN2   0.69314718055994530942f
// A pre-scale: INV_T * LOG2E * 2^23  (MFMA acc = 2^23 * log2-logit)
#define SCALE (INV_T * LOG2E * 8388608.0f)
// Schraudolph bias: (127 - 0.0432) * 2^23, balanced max rel error +-3.0%
#define BIASF 1064990828.0f

#define JC     32                           // j-chunks
#define JPC    (NROWS / JC)                 // 512 j per chunk
#define NTILES (JPC / 16)                   // 32 B-tiles per chunk
#define TT     2                            // A row-tiles per wave (32 rows)
#define WR     (TT * 16)                    // 32 rows per wave
#define NWAVE  8                            // waves per block
#define BROWS  (NWAVE * WR)                 // 256 rows per block-iteration
#define RBLOOP 2                            // row-blocks per block (amortize)
#define ROWB   (DIM * 2)                    // 128 bytes per bf16 row
#define LDSB   (JPC * ROWB)                 // 64 KiB
#define TILB   (16 * ROWB)                  // 2048 B per 16-row tile

typedef __attribute__((ext_vector_type(8))) short bf16x8;  // 8 bf16 = 4 VGPRs
typedef __attribute__((ext_vector_type(4))) float f32x4;

static __device__ __forceinline__ unsigned short f2bf(float f) {
    unsigned int u = __float_as_uint(f);
    unsigned int r = (u + 0x7fffu + ((u >> 16) & 1u)) >> 16;   // RNE
    return (unsigned short)r;
}

// ------- kernel 1: normalize rows of BOTH inputs -> bf16 (A pre-scaled) ----
__global__ __launch_bounds__(256) void nrm_bf16_kernel(
        const float* __restrict__ A, const float* __restrict__ B,
        unsigned short* __restrict__ Ab, unsigned short* __restrict__ Bb) {
    int wid  = (blockIdx.x * 256 + threadIdx.x) >> 6;   // 0..2*NROWS-1
    int lane = threadIdx.x & 63;
    const float* in;
    unsigned short* out;
    float scale;
    int row;
    if (wid < NROWS) { in = A; out = Ab; scale = SCALE; row = wid; }
    else             { in = B; out = Bb; scale = 1.0f;  row = wid - NROWS; }
    float x  = in[row * DIM + lane];
    float ss = x * x;
    #pragma unroll
    for (int m = 32; m >= 1; m >>= 1) ss += __shfl_xor(ss, m, 64);
    out[row * DIM + lane] = f2bf(x * rsqrtf(ss) * scale);
}

// -------- kernel 2: LDS-staged MFMA sim tiles + bit-exp row-sum partials ---
// One block = one 64KB j-chunk staged once + RBLOOP row-blocks of A.
__global__ __launch_bounds__(NWAVE * 64) void simexp_kernel(
        const unsigned short* __restrict__ Ab,
        const unsigned short* __restrict__ Bb,
        float* __restrict__ partials) {
    __shared__ __align__(1024) unsigned char lds[LDSB];
    const int lane = threadIdx.x & 63;
    const int wid  = threadIdx.x >> 6;                  // wave in block
    const int jc   = blockIdx.x & (JC - 1);
    const int rbb  = blockIdx.x / JC;                   // 0..31
    const int lr   = lane & 15;                         // fragment row/col
    const int lk   = lane >> 4;                         // k-group (x8 bf16)

    // ---- stage B chunk ONCE: linear LDS dest, XOR-permuted global src ----
    // LDS(row, col16) holds global(row, col16 ^ (row&7)); each instr covers
    // 8 rows (1 KiB), so row&7 == lane>>3 inside the instr.  (validated r5)
    const unsigned char* gB = (const unsigned char*)Bb + (size_t)jc * JPC * ROWB;
    const int perm = ((lane >> 3) << 7) | ((((lane & 7) ^ (lane >> 3))) << 4);
    #pragma unroll
    for (int i = 0; i < LDSB / 1024 / NWAVE; ++i) {     // 8 slabs per wave
        const int off = (wid * (LDSB / 1024 / NWAVE) + i) * 1024;
        __builtin_amdgcn_global_load_lds(
            (const __attribute__((address_space(1))) void*)(gB + off + perm),
            (__attribute__((address_space(3))) void*)(&lds[off]),
            16, 0, 0);
    }

    // ---- A fragments for row-block 0 (overlap the staging latency) -------
    bf16x8 a[TT][2];
    {
        const int i00 = rbb * RBLOOP * BROWS + wid * WR;
        #pragma unroll
        for (int t = 0; t < TT; ++t) {
            const unsigned short* ap =
                Ab + (size_t)(i00 + t * 16 + lr) * DIM + lk * 8;
            a[t][0] = *(const bf16x8*)(ap);
            a[t][1] = *(const bf16x8*)(ap + 32);
        }
    }

    // ds_read bases: row lr, col16 = lk (frag0) / lk^4 (frag1), un-swizzled
    // via the same XOR; loop-invariant since row&7 == lr&7 for every tile.
    const unsigned char* lp0 = &lds[lr * ROWB + (((lk    ) ^ (lr & 7)) << 4)];
    const unsigned char* lp1 = &lds[lr * ROWB + (((lk ^ 4) ^ (lr & 7)) << 4)];

    // MFMA C input = Schraudolph bias: acc = 2^23*x + (127-sigma)*2^23.
    const f32x4 bias = {BIASF, BIASF, BIASF, BIASF};

    // Drain the staging DMA (vmcnt only: 0x0f70 = vmcnt(0), lgkm/exp free)
    // before ANY wave crosses the barrier -- compiler-visible builtin, no
    // asm clobber (R12's clobber cost +56 VGPR).
    __builtin_amdgcn_s_waitcnt(0x0f70);
    __syncthreads();

    for (int it = 0; it < RBLOOP; ++it) {
        const int i0 = (rbb * RBLOOP + it) * BROWS + wid * WR;

        float es[TT][4];
        #pragma unroll
        for (int t = 0; t < TT; ++t)
            #pragma unroll
            for (int r = 0; r < 4; ++r) es[t][r] = 0.0f;

        // ---- prologue: tile 0 -> accp ----
        bf16x8 c0 = *(const bf16x8*)(lp0);
        bf16x8 c1 = *(const bf16x8*)(lp1);
        f32x4 accp[TT];
        #pragma unroll
        for (int t = 0; t < TT; ++t) {
            accp[t] = __builtin_amdgcn_mfma_f32_16x16x32_bf16(a[t][0], c0, bias, 0, 0, 0);
            accp[t] = __builtin_amdgcn_mfma_f32_16x16x32_bf16(a[t][1], c1, accp[t], 0, 0, 0);
        }

        // ---- steady state: ds_read(jt) | bit-exp(jt-1) | MFMA(jt) ----
        for (int jt = 1; jt < NTILES; ++jt) {
            bf16x8 n0 = *(const bf16x8*)(lp0 + jt * TILB);
            bf16x8 n1 = *(const bf16x8*)(lp1 + jt * TILB);
            #pragma unroll
            for (int t = 0; t < TT; ++t)
                #pragma unroll
                for (int r = 0; r < 4; ++r)
                    es[t][r] += __int_as_float((int)accp[t][r]);
            #pragma unroll
            for (int t = 0; t < TT; ++t) {
                accp[t] = __builtin_amdgcn_mfma_f32_16x16x32_bf16(a[t][0], n0, bias, 0, 0, 0);
                accp[t] = __builtin_amdgcn_mfma_f32_16x16x32_bf16(a[t][1], n1, accp[t], 0, 0, 0);
            }
        }
        // ---- epilogue: bit-exp of last tile ----
        #pragma unroll
        for (int t = 0; t < TT; ++t)
            #pragma unroll
            for (int r = 0; r < 4; ++r)
                es[t][r] += __int_as_float((int)accp[t][r]);

        // ---- prefetch next row-block's A fragments (hide under reduce) ---
        if (it + 1 < RBLOOP) {
            const int i0n = (rbb * RBLOOP + it + 1) * BROWS + wid * WR;
            #pragma unroll
            for (int t = 0; t < TT; ++t) {
                const unsigned short* ap =
                    Ab + (size_t)(i0n + t * 16 + lr) * DIM + lk * 8;
                a[t][0] = *(const bf16x8*)(ap);
                a[t][1] = *(const bf16x8*)(ap + 32);
            }
        }

        // ---- reduce across the 16 lanes sharing lk; write partials ----
        #pragma unroll
        for (int t = 0; t < TT; ++t)
            #pragma unroll
            for (int r = 0; r < 4; ++r) {
                float v = es[t][r];
                v += __shfl_xor(v, 1, 64);
                v += __shfl_xor(v, 2, 64);
                v += __shfl_xor(v, 4, 64);
                v += __shfl_xor(v, 8, 64);
                es[t][r] = v;
            }
        if (lr == 0) {                                  // lanes 0,16,32,48
            float* pout = partials + (size_t)jc * NROWS + i0;
            #pragma unroll
            for (int t = 0; t < TT; ++t) {
                f32x4 v = {es[t][0], es[t][1], es[t][2], es[t][3]};
                *(f32x4*)(pout + t * 16 + lk * 4) = v;  // rows lk*4..lk*4+3
            }
        }
    }
}

// -------- kernel 3: per-row loss; half-wave partial sum (JC==32) -----------
__global__ __launch_bounds__(256) void rowloss_kernel(
        const float* __restrict__ A, const float* __restrict__ B,
        const float* __restrict__ partials, float* __restrict__ rowloss) {
    int row  = (blockIdx.x * 256 + threadIdx.x) >> 6;
    int lane = threadIdx.x & 63;
    float a = A[row * DIM + lane];
    float b = B[row * DIM + lane];
    float saa = a * a, sbb = b * b, sab = a * b;
    float S = (lane < JC) ? partials[(size_t)lane * NROWS + row] : 0.0f;
    #pragma unroll
    for (int m = 32; m >= 1; m >>= 1) {
        saa += __shfl_xor(saa, m, 64);
        sbb += __shfl_xor(sbb, m, 64);
        sab += __shfl_xor(sab, m, 64);
        S   += __shfl_xor(S,   m, 64);
    }
    if (lane == 0) {
        float diag = sab * rsqrtf(saa * sbb);           // exact fp32 cos-sim
        rowloss[row] = LN2 * __builtin_amdgcn_logf(S) - diag * INV_T;
    }
}

// -------- kernel 4: deterministic mean over 16384 row losses ---------------
__global__ __launch_bounds__(1024) void mean_kernel(
        const float* __restrict__ rowloss, float* __restrict__ out) {
    float s = 0.f;
    for (int idx = threadIdx.x; idx < NROWS; idx += 1024) s += rowloss[idx];
    __shared__ float red[16];
    #pragma unroll
    for (int m = 32; m >= 1; m >>= 1) s += __shfl_xor(s, m, 64);
    if ((threadIdx.x & 63) == 0) red[threadIdx.x >> 6] = s;
    __syncthreads();
    if (threadIdx.x < 16) {
        float t = red[threadIdx.x];
        #pragma unroll
        for (int m = 8; m >= 1; m >>= 1) t += __shfl_xor(t, m, 16);
        if (threadIdx.x == 0) out[0] = t * (1.0f / NROWS);
    }
}

extern "C" void kernel_launch(void* const* d_in, const int* in_sizes, int n_in,
                              void* d_out, int out_size, void* d_ws, size_t ws_size,
                              hipStream_t stream) {
    const float* A  = (const float*)d_in[0];
    const float* Bm = (const float*)d_in[1];
    float* out = (float*)d_out;

    unsigned short* Ab = (unsigned short*)d_ws;                 // 2 MiB
    unsigned short* Bb = Ab + (size_t)NROWS * DIM;              // 2 MiB
    float* partials    = (float*)(Bb + (size_t)NROWS * DIM);    // 2 MiB
    float* rowloss     = partials + (size_t)JC * NROWS;         // 64 KiB

    nrm_bf16_kernel<<<2 * NROWS / 4, 256, 0, stream>>>(A, Bm, Ab, Bb);
    simexp_kernel<<<JC * (NROWS / (BROWS * RBLOOP)), NWAVE * 64, 0, stream>>>(
        Ab, Bb, partials);
    rowloss_kernel<<<NROWS / 4, 256, 0, stream>>>(A, Bm, partials, rowloss);
    mean_kernel<<<1, 1024, 0, stream>>>(rowloss, out);
}